// Round 1
// 308.737 us; speedup vs baseline: 1.0175x; 1.0175x over previous
//
#include <hip/hip_runtime.h>

#define DIM 1024
#define BATCH 4
#define SEQ 4096
#define NH 16
#define HD 64
#define KP 256

typedef float f32x4 __attribute__((ext_vector_type(4)));
typedef _Float16 half8 __attribute__((ext_vector_type(8)));

__device__ __forceinline__ void gll16(const void* g, void* l) {
  __builtin_amdgcn_global_load_lds(
      (const __attribute__((address_space(1))) void*)g,
      (__attribute__((address_space(3))) void*)l, 16, 0, 0);
}

// DPP row_ror:n within 16-lane rows (VALU-latency cross-lane; our reduction
// groups are exactly the 16-lane DPP rows). ctrl = 0x120|n.
#define DPPF(v, ctrl)                                                        \
  __builtin_bit_cast(float, __builtin_amdgcn_mov_dpp(                        \
                                __builtin_bit_cast(int, v), ctrl, 0xF, 0xF, true))

// ---- fp32 -> fp16 elementwise convert, 8 elems/thread ----
__global__ void k_cvt(const float* __restrict__ s, _Float16* __restrict__ d) {
  int i = (blockIdx.x * 256 + threadIdx.x) * 8;
  f32x4 a = *(const f32x4*)(s + i);
  f32x4 b = *(const f32x4*)(s + i + 4);
  half8 h;
  h[0] = a[0]; h[1] = a[1]; h[2] = a[2]; h[3] = a[3];
  h[4] = b[0]; h[5] = b[1]; h[6] = b[2]; h[7] = b[3];
  *(half8*)(d + i) = h;
}

// Wq and Wo converts merged: grid 1024 blocks
__global__ void k_cvtw(const float* __restrict__ Wq, const float* __restrict__ Wo,
                       _Float16* __restrict__ Wq_h, _Float16* __restrict__ Wo_h) {
  int bb = blockIdx.x;
  const float* s = (bb < 512) ? Wq : Wo;
  _Float16* d = (bb < 512) ? Wq_h : Wo_h;
  int i = ((bb & 511) * 256 + threadIdx.x) * 8;
  f32x4 a = *(const f32x4*)(s + i);
  f32x4 b = *(const f32x4*)(s + i + 4);
  half8 h;
  h[0] = a[0]; h[1] = a[1]; h[2] = a[2]; h[3] = a[3];
  h[4] = b[0]; h[5] = b[1]; h[6] = b[2]; h[7] = b[3];
  *(half8*)(d + i) = h;
}

// misc small work merged: grid 88 blocks
__global__ void k_misc(const float* __restrict__ E, const float* __restrict__ F,
                       _Float16* __restrict__ E_h, _Float16* __restrict__ Ft,
                       float* __restrict__ xsum) {
  int bb = blockIdx.x;
  if (bb < 16) {
    xsum[bb * 256 + threadIdx.x] = 0.f;
  } else if (bb < 24) {
    int i = ((bb - 16) * 256 + threadIdx.x) * 8;
    f32x4 a = *(const f32x4*)(E + i);
    f32x4 b = *(const f32x4*)(E + i + 4);
    half8 h;
    h[0] = a[0]; h[1] = a[1]; h[2] = a[2]; h[3] = a[3];
    h[4] = b[0]; h[5] = b[1]; h[6] = b[2]; h[7] = b[3];
    *(half8*)(E_h + i) = h;
  } else {
    int i = (bb - 24) * 256 + threadIdx.x;  // 16384
    int k = i >> 6, d = i & 63;
    Ft[d * KP + (k & 15) * 16 + (k >> 4)] = (_Float16)F[i];
  }
}

// xsum[b,c] = sum_n x[b,n,c]; reads fp16 x_h; grid (4,B,32)
__global__ void k_xsum(const _Float16* __restrict__ xh, float* __restrict__ xs) {
  int c = blockIdx.x * 256 + threadIdx.x;
  int b = blockIdx.y;
  int n0 = blockIdx.z * 128;
  const _Float16* p = xh + (size_t)(b * SEQ + n0) * DIM + c;
  float s = 0.f;
  #pragma unroll 8
  for (int i = 0; i < 128; i++) s += (float)p[i * DIM];
  atomicAdd(&xs[b * DIM + c], s);
}

// Sk[b,c] = xsum[b,:]@Wk[c,:], Sv likewise. One wave per output dot.
__global__ void k_sksv(const float* __restrict__ xs, const float* __restrict__ Wk,
                       const float* __restrict__ Wv, float* __restrict__ Sk,
                       float* __restrict__ Sv) {
  int idx = blockIdx.x * 4 + (threadIdx.x >> 6);
  int lane = threadIdx.x & 63;
  int kv = idx >> 12;
  int rem = idx & 4095;
  int b = rem >> 10, c = rem & 1023;
  const float* W = (kv ? Wv : Wk) + c * DIM;
  const float* xp = xs + b * DIM;
  float a = 0.f;
  #pragma unroll
  for (int i = 0; i < 16; i++) a += xp[lane + i * 64] * W[lane + i * 64];
  for (int off = 32; off; off >>= 1) a += __shfl_down(a, off);
  if (lane == 0) (kv ? Sv : Sk)[rem] = a;
}

// ---- fp16 MFMA GEMM, round 3 ----
// Changes vs round 2:
//  * double-buffered LDS with depth-1 prefetch (stage t+1 issued before
//    compute of t; ONE __syncthreads per K-iter instead of two) — hides the
//    global->LDS latency under ds_read+MFMA (T3-minimum template).
//  * both-sides K-chunk XOR swizzle (rule 21): global source address is
//    pre-swizzled so global_load_lds's linear LDS write lands chunk
//    c^((row>>1)&3) at slot c; reader applies the same XOR. Turns the
//    8-lanes-per-bank-quad ds_read_b128 pattern into uniform 2-way (free).
//  * epilogue LDS pads (136 fp16 / 132 f32 row stride) kill the 32-lane
//    2-slot conflict on the repack reads.
// MODE 0: out fp16 = acc * sb[b*DIM+col] * 0.125 * log2e  (Q proj)
// MODE 1: out fp32 = acc + sb[col]                        (out proj + bias)
template <int MODE>
__global__ __launch_bounds__(256) void k_gemm(const _Float16* __restrict__ A,
                                              const _Float16* __restrict__ Bw,
                                              void* __restrict__ Cout,
                                              const float* __restrict__ sb) {
  __shared__ _Float16 sh[2][2][128 * 32];  // [buf][A/B][128 rows x 32 k]
  const int tid = threadIdx.x;
  const int w = tid >> 6, lane = tid & 63;
  const int q4 = lane >> 4, mm = lane & 15;
  const int wm = w & 1, wn = w >> 1;
  const int m0 = blockIdx.x * 128, n0 = blockIdx.y * 128;
  f32x4 acc[4][4] = {};
  // staging: lane l covers (row=l>>2, chunk=l&3); fetch global chunk
  // (l&3)^((l>>3)&3) so LDS[row][c] = global[row][c ^ ((row>>1)&3)].
  const int swz_st = ((lane & 3) ^ ((lane >> 3) & 3)) * 8;
  const _Float16* Ag = A + (size_t)(m0 + w * 32 + (lane >> 2)) * DIM + swz_st;
  const _Float16* Bg = Bw + (size_t)(n0 + w * 32 + (lane >> 2)) * DIM + swz_st;
  const int woff = w * 1024;
  // reader: row R=...+mm+16t has key (R>>1)&3 = (mm>>1)&3 for all t, wm.
  const int rd_sw = (q4 ^ ((mm >> 1) & 3)) * 8;
  const int rdo_a = (wm * 64 + mm) * 32 + rd_sw;
  const int rdo_b = (wn * 64 + mm) * 32 + rd_sw;

  // prologue: stage k-tile 0 into buf 0
  gll16(Ag, sh[0][0] + woff);
  gll16(Ag + 16 * DIM, sh[0][0] + woff + 512);
  gll16(Bg, sh[0][1] + woff);
  gll16(Bg + 16 * DIM, sh[0][1] + woff + 512);
  __syncthreads();
  #pragma unroll 2
  for (int t = 0; t < 32; t++) {
    const int cur = t & 1;
    if (t < 31) {  // issue next-tile stage BEFORE compute (prefetch)
      const int k0 = (t + 1) * 32;
      _Float16* AsW = sh[cur ^ 1][0] + woff;
      _Float16* BsW = sh[cur ^ 1][1] + woff;
      gll16(Ag + k0, AsW);
      gll16(Ag + k0 + 16 * DIM, AsW + 512);
      gll16(Bg + k0, BsW);
      gll16(Bg + k0 + 16 * DIM, BsW + 512);
    }
    half8 av[4], bv[4];
    const _Float16* Ap = sh[cur][0] + rdo_a;
    const _Float16* Bp = sh[cur][1] + rdo_b;
    #pragma unroll
    for (int i = 0; i < 4; i++) {
      av[i] = *(const half8*)(Ap + i * 512);
      bv[i] = *(const half8*)(Bp + i * 512);
    }
    #pragma unroll
    for (int mt = 0; mt < 4; mt++)
      #pragma unroll
      for (int nt = 0; nt < 4; nt++)
        acc[mt][nt] = __builtin_amdgcn_mfma_f32_16x16x32_f16(av[mt], bv[nt], acc[mt][nt], 0, 0, 0);
    // single barrier: drains the prefetch (hidden under compute above) and
    // guards buf[cur^1] reuse next iteration.
    __syncthreads();
  }
  if (MODE == 0) {
    _Float16* Lh = (_Float16*)sh;  // [64][136] per phase (padded)
    #pragma unroll
    for (int p = 0; p < 2; p++) {
      if (wm == p) {
        #pragma unroll
        for (int nt = 0; nt < 4; nt++) {
          int cl = wn * 64 + nt * 16 + mm;
          float s = sb[(m0 >> 12) * DIM + n0 + cl] * (0.125f * 1.44269504088896f);
          #pragma unroll
          for (int mt = 0; mt < 4; mt++) {
            int rl = mt * 16 + q4 * 4;
            #pragma unroll
            for (int r = 0; r < 4; r++)
              Lh[(rl + r) * 136 + cl] = (_Float16)(acc[mt][nt][r] * s);
          }
        }
      }
      __syncthreads();
      int row_l = tid >> 2, c0 = (tid & 3) * 32;
      _Float16* dst = (_Float16*)Cout + (size_t)(m0 + p * 64 + row_l) * DIM + n0 + c0;
      #pragma unroll
      for (int i = 0; i < 4; i++)
        *(half8*)(dst + i * 8) = *(half8*)(Lh + row_l * 136 + c0 + i * 8);
      __syncthreads();
    }
  } else {
    float* Lf = (float*)sh;  // [32][132] per phase (padded)
    #pragma unroll
    for (int p = 0; p < 4; p++) {
      if (wm == (p >> 1)) {
        #pragma unroll
        for (int nt = 0; nt < 4; nt++) {
          int cl = wn * 64 + nt * 16 + mm;
          float s = sb[n0 + cl];
          #pragma unroll
          for (int mti = 0; mti < 2; mti++) {
            int mt = (p & 1) * 2 + mti;
            int rl = mt * 16 + q4 * 4 - (p & 1) * 32;
            #pragma unroll
            for (int r = 0; r < 4; r++)
              Lf[(rl + r) * 132 + cl] = acc[mt][nt][r] + s;
          }
        }
      }
      __syncthreads();
      int row_l = tid >> 3, c0 = (tid & 7) * 16;
      float* dst = (float*)Cout + (size_t)(m0 + p * 32 + row_l) * DIM + n0 + c0;
      #pragma unroll
      for (int i = 0; i < 4; i++)
        *(f32x4*)(dst + i * 4) = *(f32x4*)(Lf + row_l * 132 + c0 + i * 4);
      __syncthreads();
    }
  }
}

// ---- fused attention v4: grid (8,64)=512 blocks, 8 tiles/wave ----
// DPP row_ror butterflies for the 16-lane softmax reductions (VALU latency,
// not ds_bpermute's ~120cyc); P normalization deferred to the epilogue
// (out linear in P; phase-1/phase-2 C-layout row mapping identical).
__global__ __launch_bounds__(256) void k_attn(const _Float16* __restrict__ Q,
                                              const _Float16* __restrict__ E,
                                              const _Float16* __restrict__ Ftp,
                                              const float* __restrict__ Sv,
                                              _Float16* __restrict__ O) {
  __shared__ _Float16 Ps[4][16][264];
  const int tid = threadIdx.x;
  const int w = tid >> 6, lane = tid & 63;
  const int q4 = lane >> 4, mm = lane & 15;
  const int bh = blockIdx.y;
  const int b = bh >> 4, h = bh & 15;
  const int row_base = blockIdx.x * 512 + w * 128;  // 8 tiles of 16 rows

  half8 ef[16][2];
  #pragma unroll
  for (int t = 0; t < 16; t++)
    #pragma unroll
    for (int kk = 0; kk < 2; kk++)
      ef[t][kk] = *(const half8*)(E + (t * 16 + mm) * HD + kk * 32 + q4 * 8);
  half8 ff[4][8];
  #pragma unroll
  for (int nt = 0; nt < 4; nt++)
    #pragma unroll
    for (int kk = 0; kk < 8; kk++)
      ff[nt][kk] = *(const half8*)(Ftp + (nt * 16 + mm) * KP + kk * 32 + q4 * 8);
  float sv[4];
  #pragma unroll
  for (int nt = 0; nt < 4; nt++) sv[nt] = Sv[b * DIM + h * HD + nt * 16 + mm];

  const _Float16* Qbase = Q + ((size_t)(b * SEQ + row_base + mm)) * DIM + h * HD + q4 * 8;
  half8 qa0 = *(const half8*)(Qbase);
  half8 qa1 = *(const half8*)(Qbase + 32);

  for (int tile = 0; tile < 8; tile++) {
    f32x4 acc[16] = {};
    #pragma unroll
    for (int t = 0; t < 16; t++)
      acc[t] = __builtin_amdgcn_mfma_f32_16x16x32_f16(qa0, ef[t][0], acc[t], 0, 0, 0);
    #pragma unroll
    for (int t = 0; t < 16; t++)
      acc[t] = __builtin_amdgcn_mfma_f32_16x16x32_f16(qa1, ef[t][1], acc[t], 0, 0, 0);
    half8 qn0, qn1;
    if (tile < 7) {
      const _Float16* Qn = Qbase + (size_t)(tile + 1) * 16 * DIM;
      qn0 = *(const half8*)(Qn);
      qn1 = *(const half8*)(Qn + 32);
    }
    // rowwise max over 256 cols (base-2 logits; log2e folded upstream)
    float mx[4] = {-1e30f, -1e30f, -1e30f, -1e30f};
    #pragma unroll
    for (int t = 0; t < 16; t++)
      #pragma unroll
      for (int r = 0; r < 4; r++) mx[r] = fmaxf(mx[r], acc[t][r]);
    #pragma unroll
    for (int r = 0; r < 4; r++) {
      float m = mx[r];
      m = fmaxf(m, DPPF(m, 0x121));  // row_ror:1
      m = fmaxf(m, DPPF(m, 0x122));  // row_ror:2
      m = fmaxf(m, DPPF(m, 0x124));  // row_ror:4
      m = fmaxf(m, DPPF(m, 0x128));  // row_ror:8
      mx[r] = m;
    }
    float sm[4] = {0.f, 0.f, 0.f, 0.f};
    #pragma unroll
    for (int t = 0; t < 16; t++)
      #pragma unroll
      for (int r = 0; r < 4; r++) {
        float p = __builtin_amdgcn_exp2f(acc[t][r] - mx[r]);
        acc[t][r] = p;
        sm[r] += p;
      }
    #pragma unroll
    for (int r = 0; r < 4; r++) {
      float s = sm[r];
      s += DPPF(s, 0x121);
      s += DPPF(s, 0x122);
      s += DPPF(s, 0x124);
      s += DPPF(s, 0x128);
      sm[r] = 1.f / s;
    }
    // unnormalized P -> LDS (permuted-col layout; normalize in epilogue)
    #pragma unroll
    for (int r = 0; r < 4; r++) {
      half8 h0, h1;
      #pragma unroll
      for (int t = 0; t < 8; t++) h0[t] = (_Float16)acc[t][r];
      #pragma unroll
      for (int t = 0; t < 8; t++) h1[t] = (_Float16)acc[t + 8][r];
      *(half8*)&Ps[w][q4 * 4 + r][mm * 16] = h0;
      *(half8*)&Ps[w][q4 * 4 + r][mm * 16 + 8] = h1;
    }
    // phase 2: out = P @ F (permuted k-order), scale by sm[r]*sv[nt] at write
    f32x4 acc2[4] = {};
    #pragma unroll
    for (int kk = 0; kk < 8; kk++) {
      half8 pa = *(const half8*)&Ps[w][mm][kk * 32 + q4 * 8];
      #pragma unroll
      for (int nt = 0; nt < 4; nt++)
        acc2[nt] = __builtin_amdgcn_mfma_f32_16x16x32_f16(pa, ff[nt][kk], acc2[nt], 0, 0, 0);
    }
    const int rw0 = row_base + tile * 16;
    #pragma unroll
    for (int nt = 0; nt < 4; nt++)
      #pragma unroll
      for (int r = 0; r < 4; r++)
        O[(size_t)(b * SEQ + rw0 + q4 * 4 + r) * DIM + h * HD + nt * 16 + mm] =
            (_Float16)(acc2[nt][r] * (sm[r] * sv[nt]));
    qa0 = qn0;
    qa1 = qn1;
  }
}

extern "C" void kernel_launch(void* const* d_in, const int* in_sizes, int n_in,
                              void* d_out, int out_size, void* d_ws, size_t ws_size,
                              hipStream_t stream) {
  (void)in_sizes; (void)n_in; (void)out_size; (void)ws_size;
  const float* x  = (const float*)d_in[0];
  const float* Wq = (const float*)d_in[1];
  const float* Wk = (const float*)d_in[2];
  const float* Wv = (const float*)d_in[3];
  const float* E  = (const float*)d_in[4];
  const float* F  = (const float*)d_in[5];
  const float* Wo = (const float*)d_in[6];
  const float* bo = (const float*)d_in[7];
  char* ws = (char*)d_ws;
  _Float16* x_h  = (_Float16*)(ws);
  _Float16* O_h  = (_Float16*)(ws);          // aliases x_h (dead after Q GEMM)
  _Float16* Q_h  = (_Float16*)(ws + 33554432);
  _Float16* Wq_h = (_Float16*)(ws + 67108864);
  _Float16* Wo_h = (_Float16*)(ws + 69206016);
  _Float16* E_h  = (_Float16*)(ws + 71303168);
  _Float16* Ft_h = (_Float16*)(ws + 71335936);
  float* xsum    = (float*)(ws + 71368704);
  float* Sk      = (float*)(ws + 71385088);
  float* Sv      = (float*)(ws + 71401472);
  float* out     = (float*)d_out;

  k_cvt<<<8192, 256, 0, stream>>>(x, x_h);
  k_misc<<<88, 256, 0, stream>>>(E, F, E_h, Ft_h, xsum);
  k_cvtw<<<1024, 256, 0, stream>>>(Wq, Wo, Wq_h, Wo_h);
  k_xsum<<<dim3(4, BATCH, 32), 256, 0, stream>>>(x_h, xsum);
  k_sksv<<<2048, 256, 0, stream>>>(xsum, Wk, Wv, Sk, Sv);
  k_gemm<0><<<dim3(128, 8), 256, 0, stream>>>(x_h, Wq_h, (void*)Q_h, Sk);
  k_attn<<<dim3(8, 64), 256, 0, stream>>>(Q_h, E_h, Ft_h, Sv, O_h);
  k_gemm<1><<<dim3(128, 8), 256, 0, stream>>>(O_h, Wo_h, (void*)out, bo);
}

// Round 2
// 294.185 us; speedup vs baseline: 1.0678x; 1.0495x over previous
//
#include <hip/hip_runtime.h>

#define DIM 1024
#define BATCH 4
#define SEQ 4096
#define NH 16
#define HD 64
#define KP 256

typedef float f32x4 __attribute__((ext_vector_type(4)));
typedef _Float16 half8 __attribute__((ext_vector_type(8)));

__device__ __forceinline__ void gll16(const void* g, void* l) {
  __builtin_amdgcn_global_load_lds(
      (const __attribute__((address_space(1))) void*)g,
      (__attribute__((address_space(3))) void*)l, 16, 0, 0);
}

// DPP row_ror:n within 16-lane rows (VALU-latency cross-lane; our reduction
// groups are exactly the 16-lane DPP rows). ctrl = 0x120|n.
#define DPPF(v, ctrl)                                                        \
  __builtin_bit_cast(float, __builtin_amdgcn_mov_dpp(                        \
                                __builtin_bit_cast(int, v), ctrl, 0xF, 0xF, true))

// ---- fp32 -> fp16 elementwise convert, 8 elems/thread ----
__global__ void k_cvt(const float* __restrict__ s, _Float16* __restrict__ d) {
  int i = (blockIdx.x * 256 + threadIdx.x) * 8;
  f32x4 a = *(const f32x4*)(s + i);
  f32x4 b = *(const f32x4*)(s + i + 4);
  half8 h;
  h[0] = a[0]; h[1] = a[1]; h[2] = a[2]; h[3] = a[3];
  h[4] = b[0]; h[5] = b[1]; h[6] = b[2]; h[7] = b[3];
  *(half8*)(d + i) = h;
}

// Wq and Wo converts merged: grid 1024 blocks
__global__ void k_cvtw(const float* __restrict__ Wq, const float* __restrict__ Wo,
                       _Float16* __restrict__ Wq_h, _Float16* __restrict__ Wo_h) {
  int bb = blockIdx.x;
  const float* s = (bb < 512) ? Wq : Wo;
  _Float16* d = (bb < 512) ? Wq_h : Wo_h;
  int i = ((bb & 511) * 256 + threadIdx.x) * 8;
  f32x4 a = *(const f32x4*)(s + i);
  f32x4 b = *(const f32x4*)(s + i + 4);
  half8 h;
  h[0] = a[0]; h[1] = a[1]; h[2] = a[2]; h[3] = a[3];
  h[4] = b[0]; h[5] = b[1]; h[6] = b[2]; h[7] = b[3];
  *(half8*)(d + i) = h;
}

// misc small work merged: grid 88 blocks
__global__ void k_misc(const float* __restrict__ E, const float* __restrict__ F,
                       _Float16* __restrict__ E_h, _Float16* __restrict__ Ft,
                       float* __restrict__ xsum) {
  int bb = blockIdx.x;
  if (bb < 16) {
    xsum[bb * 256 + threadIdx.x] = 0.f;
  } else if (bb < 24) {
    int i = ((bb - 16) * 256 + threadIdx.x) * 8;
    f32x4 a = *(const f32x4*)(E + i);
    f32x4 b = *(const f32x4*)(E + i + 4);
    half8 h;
    h[0] = a[0]; h[1] = a[1]; h[2] = a[2]; h[3] = a[3];
    h[4] = b[0]; h[5] = b[1]; h[6] = b[2]; h[7] = b[3];
    *(half8*)(E_h + i) = h;
  } else {
    int i = (bb - 24) * 256 + threadIdx.x;  // 16384
    int k = i >> 6, d = i & 63;
    Ft[d * KP + (k & 15) * 16 + (k >> 4)] = (_Float16)F[i];
  }
}

// xsum[b,c] = sum_n x[b,n,c]; reads fp16 x_h; grid (4,B,32)
__global__ void k_xsum(const _Float16* __restrict__ xh, float* __restrict__ xs) {
  int c = blockIdx.x * 256 + threadIdx.x;
  int b = blockIdx.y;
  int n0 = blockIdx.z * 128;
  const _Float16* p = xh + (size_t)(b * SEQ + n0) * DIM + c;
  float s = 0.f;
  #pragma unroll 8
  for (int i = 0; i < 128; i++) s += (float)p[i * DIM];
  atomicAdd(&xs[b * DIM + c], s);
}

// Sk[b,c] = xsum[b,:]@Wk[c,:], Sv likewise. One wave per output dot.
__global__ void k_sksv(const float* __restrict__ xs, const float* __restrict__ Wk,
                       const float* __restrict__ Wv, float* __restrict__ Sk,
                       float* __restrict__ Sv) {
  int idx = blockIdx.x * 4 + (threadIdx.x >> 6);
  int lane = threadIdx.x & 63;
  int kv = idx >> 12;
  int rem = idx & 4095;
  int b = rem >> 10, c = rem & 1023;
  const float* W = (kv ? Wv : Wk) + c * DIM;
  const float* xp = xs + b * DIM;
  float a = 0.f;
  #pragma unroll
  for (int i = 0; i < 16; i++) a += xp[lane + i * 64] * W[lane + i * 64];
  for (int off = 32; off; off >>= 1) a += __shfl_down(a, off);
  if (lane == 0) (kv ? Sv : Sk)[rem] = a;
}

// ---- fp16 MFMA GEMM, round 4: 256x256 tile, 8 waves, counted-vmcnt ring ----
// BK=32, ring of 4 K-tile buffers (128KB LDS). While tile t (buf t&3) is
// read, tile t+2 stages into buf (t+2)&3 (last read at t-2: race-free by
// construction). Two phases per K-tile, 16 MFMA each; raw s_barrier pairs;
// setprio(1) around MFMA (T5); vmcnt(4) ONCE per K-tile boundary — the
// newest 4 gll16 (tile t+2) stay in flight across barriers (T4: never
// drain to 0 in the loop). Both-sides chunk XOR swizzle (rule 21) carried
// over from round 3 (measured conflict-free).
// Wave (w): wm=w&1 row-half (128 rows), wn=w>>1 col-quarter (64 cols).
// MODE 0: out fp16 = acc * sb[b*DIM+col] * 0.125 * log2e  (Q proj)
// MODE 1: out fp32 = acc + sb[col]                        (out proj + bias)
template <int MODE>
__global__ __launch_bounds__(512, 2) void k_gemm(const _Float16* __restrict__ A,
                                                 const _Float16* __restrict__ Bw,
                                                 void* __restrict__ Cout,
                                                 const float* __restrict__ sb) {
  __shared__ _Float16 sh[4][2][8192];  // [ring][A=0/B=1][256 rows x 32 k]
  const int tid = threadIdx.x;
  const int w = tid >> 6, l = tid & 63;
  const int q4 = l >> 4, mm = l & 15;
  const int wm = w & 1, wn = w >> 1;
  const int m0 = blockIdx.x * 256, n0 = blockIdx.y * 256;
  f32x4 acc[8][4] = {};

  // staging: lds chunk c = w*128+u*64+l -> row=c>>2, chunk=c&3; source is
  // pre-swizzled so LDS[row][c] = global[row][c ^ ((row>>1)&3)].
  const int schunk = ((l & 3) ^ ((l >> 3) & 3)) * 8;
  const _Float16* Ag = A + (size_t)(m0 + w * 32 + (l >> 2)) * DIM + schunk;
  const _Float16* Bg = Bw + (size_t)(n0 + w * 32 + (l >> 2)) * DIM + schunk;
  const int sdst = w * 1024;
  // reader: global chunk q4 of row r is stored at chunk q4 ^ ((r>>1)&3);
  // (r>>1)&3 == (mm>>1)&3 for all frag rows.
  const int csw = (q4 ^ ((mm >> 1) & 3)) * 8;
  const int rdo_a = (wm * 128 + mm) * 32 + csw;
  const int rdo_b = (wn * 64 + mm) * 32 + csw;

  // prologue: stage K-tiles 0 and 1; wait tile 0 only (4 newest in flight)
  gll16(Ag, &sh[0][0][sdst]);
  gll16(Ag + 16 * DIM, &sh[0][0][sdst + 512]);
  gll16(Bg, &sh[0][1][sdst]);
  gll16(Bg + 16 * DIM, &sh[0][1][sdst + 512]);
  gll16(Ag + 32, &sh[1][0][sdst]);
  gll16(Ag + 32 + 16 * DIM, &sh[1][0][sdst + 512]);
  gll16(Bg + 32, &sh[1][1][sdst]);
  gll16(Bg + 32 + 16 * DIM, &sh[1][1][sdst + 512]);
  asm volatile("s_waitcnt vmcnt(4)" ::: "memory");
  __builtin_amdgcn_s_barrier();

  for (int o4 = 0; o4 < 32; o4 += 4) {
    #pragma unroll
    for (int s = 0; s < 4; s++) {
      const int t = o4 + s;
      const int rs = (s + 2) & 3;
      const _Float16* Ap = &sh[s][0][rdo_a];
      const _Float16* Bp = &sh[s][1][rdo_b];
      const int kn = (t + 2) * 32;
      half8 av[4], bv[4];
      // ---- phase A: frags (A mt0-3 + B all) + stage A of t+2 ----
      #pragma unroll
      for (int i = 0; i < 4; i++) av[i] = *(const half8*)(Ap + i * 512);
      #pragma unroll
      for (int i = 0; i < 4; i++) bv[i] = *(const half8*)(Bp + i * 512);
      if (t < 30) {
        gll16(Ag + kn, &sh[rs][0][sdst]);
        gll16(Ag + kn + 16 * DIM, &sh[rs][0][sdst + 512]);
      }
      __builtin_amdgcn_s_barrier();
      asm volatile("s_waitcnt lgkmcnt(0)" ::: "memory");
      __builtin_amdgcn_sched_barrier(0);
      __builtin_amdgcn_s_setprio(1);
      #pragma unroll
      for (int mt = 0; mt < 4; mt++)
        #pragma unroll
        for (int nt = 0; nt < 4; nt++)
          acc[mt][nt] = __builtin_amdgcn_mfma_f32_16x16x32_f16(av[mt], bv[nt], acc[mt][nt], 0, 0, 0);
      __builtin_amdgcn_s_setprio(0);
      __builtin_amdgcn_s_barrier();
      // ---- phase B: frags (A mt4-7, reuse bv) + stage B of t+2 ----
      #pragma unroll
      for (int i = 0; i < 4; i++) av[i] = *(const half8*)(Ap + 2048 + i * 512);
      if (t < 30) {
        gll16(Bg + kn, &sh[rs][1][sdst]);
        gll16(Bg + kn + 16 * DIM, &sh[rs][1][sdst + 512]);
      }
      __builtin_amdgcn_s_barrier();
      asm volatile("s_waitcnt lgkmcnt(0)" ::: "memory");
      __builtin_amdgcn_sched_barrier(0);
      __builtin_amdgcn_s_setprio(1);
      #pragma unroll
      for (int mt = 0; mt < 4; mt++)
        #pragma unroll
        for (int nt = 0; nt < 4; nt++)
          acc[mt + 4][nt] = __builtin_amdgcn_mfma_f32_16x16x32_f16(av[mt], bv[nt], acc[mt + 4][nt], 0, 0, 0);
      __builtin_amdgcn_s_setprio(0);
      // K-tile boundary: tile t+1 (staged during t-1) must be landed; the
      // newest 4 loads (tile t+2, staged this group) stay in flight.
      if (t < 30) {
        asm volatile("s_waitcnt vmcnt(4)" ::: "memory");
      } else if (t == 30) {
        asm volatile("s_waitcnt vmcnt(0)" ::: "memory");
      }
      __builtin_amdgcn_s_barrier();
    }
  }

  if (MODE == 0) {
    _Float16* Lh = (_Float16*)sh;  // [64][264] fp16 per phase (padded)
    const float lsc = 0.125f * 1.44269504088896f;
    #pragma unroll
    for (int p = 0; p < 4; p++) {
      if (wm == (p >> 1)) {
        #pragma unroll
        for (int nt = 0; nt < 4; nt++) {
          const int cl = wn * 64 + nt * 16 + mm;
          const float s = sb[(m0 >> 12) * DIM + n0 + cl] * lsc;
          #pragma unroll
          for (int mtl = 0; mtl < 4; mtl++) {
            const int mt = (p & 1) * 4 + mtl;
            const int rl = mtl * 16 + q4 * 4;
            #pragma unroll
            for (int r = 0; r < 4; r++)
              Lh[(rl + r) * 264 + cl] = (_Float16)(acc[mt][nt][r] * s);
          }
        }
      }
      __syncthreads();
      const int row_l = tid >> 3, c0 = (tid & 7) * 32;
      _Float16* dst = (_Float16*)Cout + (size_t)(m0 + p * 64 + row_l) * DIM + n0 + c0;
      #pragma unroll
      for (int i = 0; i < 4; i++)
        *(half8*)(dst + i * 8) = *(half8*)(Lh + row_l * 264 + c0 + i * 8);
      __syncthreads();
    }
  } else {
    float* Lf = (float*)sh;  // [32][260] f32 per phase (padded)
    #pragma unroll
    for (int p = 0; p < 8; p++) {
      if (wm == (p >> 2)) {
        #pragma unroll
        for (int nt = 0; nt < 4; nt++) {
          const int cl = wn * 64 + nt * 16 + mm;
          const float s = sb[n0 + cl];
          #pragma unroll
          for (int mtl = 0; mtl < 2; mtl++) {
            const int mt = (p & 3) * 2 + mtl;
            const int rl = mtl * 16 + q4 * 4;
            #pragma unroll
            for (int r = 0; r < 4; r++)
              Lf[(rl + r) * 260 + cl] = acc[mt][nt][r] + s;
          }
        }
      }
      __syncthreads();
      const int row_l = tid >> 4, c0 = (tid & 15) * 16;
      float* dst = (float*)Cout + (size_t)(m0 + p * 32 + row_l) * DIM + n0 + c0;
      #pragma unroll
      for (int i = 0; i < 4; i++)
        *(f32x4*)(dst + i * 4) = *(f32x4*)(Lf + row_l * 260 + c0 + i * 4);
      __syncthreads();
    }
  }
}

// ---- fused attention v4: grid (8,64)=512 blocks, 8 tiles/wave ----
// DPP row_ror butterflies for the 16-lane softmax reductions (VALU latency,
// not ds_bpermute's ~120cyc); P normalization deferred to the epilogue
// (out linear in P; phase-1/phase-2 C-layout row mapping identical).
__global__ __launch_bounds__(256) void k_attn(const _Float16* __restrict__ Q,
                                              const _Float16* __restrict__ E,
                                              const _Float16* __restrict__ Ftp,
                                              const float* __restrict__ Sv,
                                              _Float16* __restrict__ O) {
  __shared__ _Float16 Ps[4][16][264];
  const int tid = threadIdx.x;
  const int w = tid >> 6, lane = tid & 63;
  const int q4 = lane >> 4, mm = lane & 15;
  const int bh = blockIdx.y;
  const int b = bh >> 4, h = bh & 15;
  const int row_base = blockIdx.x * 512 + w * 128;  // 8 tiles of 16 rows

  half8 ef[16][2];
  #pragma unroll
  for (int t = 0; t < 16; t++)
    #pragma unroll
    for (int kk = 0; kk < 2; kk++)
      ef[t][kk] = *(const half8*)(E + (t * 16 + mm) * HD + kk * 32 + q4 * 8);
  half8 ff[4][8];
  #pragma unroll
  for (int nt = 0; nt < 4; nt++)
    #pragma unroll
    for (int kk = 0; kk < 8; kk++)
      ff[nt][kk] = *(const half8*)(Ftp + (nt * 16 + mm) * KP + kk * 32 + q4 * 8);
  float sv[4];
  #pragma unroll
  for (int nt = 0; nt < 4; nt++) sv[nt] = Sv[b * DIM + h * HD + nt * 16 + mm];

  const _Float16* Qbase = Q + ((size_t)(b * SEQ + row_base + mm)) * DIM + h * HD + q4 * 8;
  half8 qa0 = *(const half8*)(Qbase);
  half8 qa1 = *(const half8*)(Qbase + 32);

  for (int tile = 0; tile < 8; tile++) {
    f32x4 acc[16] = {};
    #pragma unroll
    for (int t = 0; t < 16; t++)
      acc[t] = __builtin_amdgcn_mfma_f32_16x16x32_f16(qa0, ef[t][0], acc[t], 0, 0, 0);
    #pragma unroll
    for (int t = 0; t < 16; t++)
      acc[t] = __builtin_amdgcn_mfma_f32_16x16x32_f16(qa1, ef[t][1], acc[t], 0, 0, 0);
    half8 qn0, qn1;
    if (tile < 7) {
      const _Float16* Qn = Qbase + (size_t)(tile + 1) * 16 * DIM;
      qn0 = *(const half8*)(Qn);
      qn1 = *(const half8*)(Qn + 32);
    }
    // rowwise max over 256 cols (base-2 logits; log2e folded upstream)
    float mx[4] = {-1e30f, -1e30f, -1e30f, -1e30f};
    #pragma unroll
    for (int t = 0; t < 16; t++)
      #pragma unroll
      for (int r = 0; r < 4; r++) mx[r] = fmaxf(mx[r], acc[t][r]);
    #pragma unroll
    for (int r = 0; r < 4; r++) {
      float m = mx[r];
      m = fmaxf(m, DPPF(m, 0x121));  // row_ror:1
      m = fmaxf(m, DPPF(m, 0x122));  // row_ror:2
      m = fmaxf(m, DPPF(m, 0x124));  // row_ror:4
      m = fmaxf(m, DPPF(m, 0x128));  // row_ror:8
      mx[r] = m;
    }
    float sm[4] = {0.f, 0.f, 0.f, 0.f};
    #pragma unroll
    for (int t = 0; t < 16; t++)
      #pragma unroll
      for (int r = 0; r < 4; r++) {
        float p = __builtin_amdgcn_exp2f(acc[t][r] - mx[r]);
        acc[t][r] = p;
        sm[r] += p;
      }
    #pragma unroll
    for (int r = 0; r < 4; r++) {
      float s = sm[r];
      s += DPPF(s, 0x121);
      s += DPPF(s, 0x122);
      s += DPPF(s, 0x124);
      s += DPPF(s, 0x128);
      sm[r] = 1.f / s;
    }
    // unnormalized P -> LDS (permuted-col layout; normalize in epilogue)
    #pragma unroll
    for (int r = 0; r < 4; r++) {
      half8 h0, h1;
      #pragma unroll
      for (int t = 0; t < 8; t++) h0[t] = (_Float16)acc[t][r];
      #pragma unroll
      for (int t = 0; t < 8; t++) h1[t] = (_Float16)acc[t + 8][r];
      *(half8*)&Ps[w][q4 * 4 + r][mm * 16] = h0;
      *(half8*)&Ps[w][q4 * 4 + r][mm * 16 + 8] = h1;
    }
    // phase 2: out = P @ F (permuted k-order), scale by sm[r]*sv[nt] at write
    f32x4 acc2[4] = {};
    #pragma unroll
    for (int kk = 0; kk < 8; kk++) {
      half8 pa = *(const half8*)&Ps[w][mm][kk * 32 + q4 * 8];
      #pragma unroll
      for (int nt = 0; nt < 4; nt++)
        acc2[nt] = __builtin_amdgcn_mfma_f32_16x16x32_f16(pa, ff[nt][kk], acc2[nt], 0, 0, 0);
    }
    const int rw0 = row_base + tile * 16;
    #pragma unroll
    for (int nt = 0; nt < 4; nt++)
      #pragma unroll
      for (int r = 0; r < 4; r++)
        O[(size_t)(b * SEQ + rw0 + q4 * 4 + r) * DIM + h * HD + nt * 16 + mm] =
            (_Float16)(acc2[nt][r] * (sm[r] * sv[nt]));
    qa0 = qn0;
    qa1 = qn1;
  }
}

extern "C" void kernel_launch(void* const* d_in, const int* in_sizes, int n_in,
                              void* d_out, int out_size, void* d_ws, size_t ws_size,
                              hipStream_t stream) {
  (void)in_sizes; (void)n_in; (void)out_size; (void)ws_size;
  const float* x  = (const float*)d_in[0];
  const float* Wq = (const float*)d_in[1];
  const float* Wk = (const float*)d_in[2];
  const float* Wv = (const float*)d_in[3];
  const float* E  = (const float*)d_in[4];
  const float* F  = (const float*)d_in[5];
  const float* Wo = (const float*)d_in[6];
  const float* bo = (const float*)d_in[7];
  char* ws = (char*)d_ws;
  _Float16* x_h  = (_Float16*)(ws);
  _Float16* O_h  = (_Float16*)(ws);          // aliases x_h (dead after Q GEMM)
  _Float16* Q_h  = (_Float16*)(ws + 33554432);
  _Float16* Wq_h = (_Float16*)(ws + 67108864);
  _Float16* Wo_h = (_Float16*)(ws + 69206016);
  _Float16* E_h  = (_Float16*)(ws + 71303168);
  _Float16* Ft_h = (_Float16*)(ws + 71335936);
  float* xsum    = (float*)(ws + 71368704);
  float* Sk      = (float*)(ws + 71385088);
  float* Sv      = (float*)(ws + 71401472);
  float* out     = (float*)d_out;

  k_cvt<<<8192, 256, 0, stream>>>(x, x_h);
  k_misc<<<88, 256, 0, stream>>>(E, F, E_h, Ft_h, xsum);
  k_cvtw<<<1024, 256, 0, stream>>>(Wq, Wo, Wq_h, Wo_h);
  k_xsum<<<dim3(4, BATCH, 32), 256, 0, stream>>>(x_h, xsum);
  k_sksv<<<2048, 256, 0, stream>>>(xsum, Wk, Wv, Sk, Sv);
  k_gemm<0><<<dim3(64, 4), 512, 0, stream>>>(x_h, Wq_h, (void*)Q_h, Sk);
  k_attn<<<dim3(8, 64), 256, 0, stream>>>(Q_h, E_h, Ft_h, Sv, O_h);
  k_gemm<1><<<dim3(64, 4), 512, 0, stream>>>(O_h, Wo_h, (void*)out, bo);
}